// Round 21
// baseline (125.857 us; speedup 1.0000x reference)
//
#include <hip/hip_runtime.h>

typedef unsigned short u16;
typedef unsigned int   u32;
typedef __attribute__((ext_vector_type(8))) __bf16 bf16x8;
typedef __attribute__((ext_vector_type(4))) float  f32x4;
typedef __attribute__((ext_vector_type(4))) u32    u32x4;

#define AS1q __attribute__((address_space(1)))
#define AS3q __attribute__((address_space(3)))

static __device__ __forceinline__ u16 f2bf(float f) {
    u32 u = __builtin_bit_cast(u32, f);
    u32 r = u + 0x7FFFu + ((u >> 16) & 1u);   // round-to-nearest-even
    return (u16)(r >> 16);
}

static __device__ __forceinline__ bf16x8 ld16(const u16* p) {
    return __builtin_bit_cast(bf16x8, *(const float4*)(const void*)p);
}

static __device__ __forceinline__ f32x4 mfma16(bf16x8 a, bf16x8 b, f32x4 c) {
    return __builtin_amdgcn_mfma_f32_16x16x32_bf16(a, b, c, 0, 0, 0);
}

static __device__ __forceinline__ void gld16(const u16* g, u16* l) {
    __builtin_amdgcn_global_load_lds((const AS1q u32*)g, (AS3q u32*)l, 16, 0, 0);
}

static __device__ __forceinline__ float exp2_fast(float v) {
    float e;
    asm("v_exp_f32 %0, %1" : "=v"(e) : "v"(v));
    return e;
}

static __device__ __forceinline__ u32 cvtpk(float lo, float hi_) {
    u32 d;
    asm("v_cvt_pk_bf16_f32 %0, %1, %2" : "=v"(d) : "v"(lo), "v"(hi_));
    return d;
}

static __device__ __forceinline__ u32 pack2(float a, float b) {
    return (u32)f2bf(a) | ((u32)f2bf(b) << 16);
}

// ---------------- fused prep: cast x -> bf16 (2 float4/thread), transpose+cast weights ----------------
// blocks [0,2048): cast x (524288 threads x 2 float4). [2048,2816): w_qkv^T. [2816,3072): w_proj^T.
__global__ __launch_bounds__(256) void k_prep(const float* __restrict__ x, u16* __restrict__ xb,
                                              const float* __restrict__ wqkv, u16* __restrict__ wqkvT,
                                              const float* __restrict__ wproj, u16* __restrict__ wprojT) {
    __shared__ float tile[32][33];
    int bid = blockIdx.x, tid = threadIdx.x;
    if (bid < 2048) {
        int i = bid * 256 + tid;                 // 0..524287
        float4 v0 = ((const float4*)x)[2 * i];
        float4 v1 = ((const float4*)x)[2 * i + 1];
        u32x4 o;
        o[0] = pack2(v0.x, v0.y); o[1] = pack2(v0.z, v0.w);
        o[2] = pack2(v1.x, v1.y); o[3] = pack2(v1.z, v1.w);
        ((u32x4*)xb)[i] = o;
        return;
    }
    const float* in; u16* out; int K, Nn, bx, by;
    if (bid < 2816) {
        int b2 = bid - 2048;            // w_qkv: 1536 x 512 -> [1536][512]
        in = wqkv; out = wqkvT; K = 512; Nn = 1536;
        bx = b2 % 48; by = b2 / 48;
    } else {
        int b3 = bid - 2816;            // w_proj: 512 x 512
        in = wproj; out = wprojT; K = 512; Nn = 512;
        bx = b3 % 16; by = b3 / 16;
    }
    int tx = tid & 31, ty = tid >> 5;
    int k0 = by * 32, n0 = bx * 32;
#pragma unroll
    for (int i = 0; i < 4; ++i)
        tile[ty + i * 8][tx] = in[(k0 + ty + i * 8) * Nn + n0 + tx];
    __syncthreads();
#pragma unroll
    for (int i = 0; i < 4; ++i)
        out[(n0 + ty + i * 8) * K + k0 + tx] = f2bf(tile[tx][ty + i * 8]);
}

// ---------- shared GEMM pieces: XOR-swizzled LDS staging ----------
static __device__ __forceinline__ void stage128x64(const u16* __restrict__ gbase, int ld,
                                                   u16* lds, int tid) {
    int wid = tid >> 6;
#pragma unroll
    for (int i = 0; i < 4; ++i) {
        int idx = i * 256 + tid;
        int row = idx >> 3, c8 = idx & 7;
        int csw = c8 ^ (row & 7);
        gld16(gbase + row * ld + csw * 8, lds + (i * 256 + wid * 64) * 8);
    }
}

static __device__ __forceinline__ void stage64x64(const u16* __restrict__ gbase, int ld,
                                                  u16* lds, int tid) {
    int wid = tid >> 6;
#pragma unroll
    for (int i = 0; i < 2; ++i) {
        int idx = i * 256 + tid;
        int row = idx >> 3, c8 = idx & 7;
        int csw = c8 ^ (row & 7);
        gld16(gbase + row * ld + csw * 8, lds + (i * 256 + wid * 64) * 8);
    }
}

static __device__ __forceinline__ bf16x8 frag(const u16* lds, int row, int col16) {
    return ld16(lds + row * 64 + ((col16 ^ (row & 7)) << 3));
}

// ---------------- GEMM1: qkv = xb @ wqkvT^T, scatter to Q/K/VT bf16 ----------------
// Q pre-scaled by 0.125*log2(e). V blocks (tn>=8) store VT via ushort4 (4 consecutive nseq).
__global__ __launch_bounds__(256) void k_gemm_qkv(const u16* __restrict__ xb, const u16* __restrict__ wT,
                                                  u16* __restrict__ Qh, u16* __restrict__ Kh,
                                                  u16* __restrict__ VTh) {
    __shared__ __align__(16) u16 at[128 * 64];
    __shared__ __align__(16) u16 bt[128 * 64];
    int tid = threadIdx.x, lane = tid & 63, wid = tid >> 6;
    int tm = blockIdx.x / 12, tn = blockIdx.x % 12;
    int rb = tm * 128, cb = tn * 128;
    int wr = (wid >> 1) * 64, wc = (wid & 1) * 64;
    int l15 = lane & 15, lhi = lane >> 4;
    f32x4 acc[4][4] = {};
    for (int kk = 0; kk < 512; kk += 64) {
        stage128x64(xb + rb * 512 + kk, 512, at, tid);
        stage128x64(wT + cb * 512 + kk, 512, bt, tid);
        __syncthreads();
        bf16x8 af[4][2], bfr[4][2];
#pragma unroll
        for (int m = 0; m < 4; ++m) {
            int row = wr + m * 16 + l15;
            af[m][0] = frag(at, row, lhi);
            af[m][1] = frag(at, row, 4 + lhi);
        }
#pragma unroll
        for (int n = 0; n < 4; ++n) {
            int row = wc + n * 16 + l15;
            bfr[n][0] = frag(bt, row, lhi);
            bfr[n][1] = frag(bt, row, 4 + lhi);
        }
#pragma unroll
        for (int m = 0; m < 4; ++m)
#pragma unroll
            for (int n = 0; n < 4; ++n) {
                acc[m][n] = mfma16(af[m][0], bfr[n][0], acc[m][n]);
                acc[m][n] = mfma16(af[m][1], bfr[n][1], acc[m][n]);
            }
        __syncthreads();
    }
    if (tn >= 8) {
        // pure-V block: for fixed (m,n) the 4 r-values are 4 consecutive nseq in VT -> one 8B store
#pragma unroll
        for (int m = 0; m < 4; ++m)
#pragma unroll
            for (int n = 0; n < 4; ++n) {
                ushort4 o4;
                o4.x = f2bf(acc[m][n][0]); o4.y = f2bf(acc[m][n][1]);
                o4.z = f2bf(acc[m][n][2]); o4.w = f2bf(acc[m][n][3]);
                int R0 = rb + wr + m * 16 + lhi * 4;          // nseq base (mult of 4)
                int Cg = cb + wc + n * 16 + l15;
                int b = R0 >> 11, nseq = R0 & 2047;
                int rm = Cg & 511, h = rm >> 6, d = rm & 63;
                int bh = (b << 3) + h;
                *(ushort4*)&VTh[(bh * 64 + d) * 2048 + nseq] = o4;
            }
    } else {
#pragma unroll
        for (int m = 0; m < 4; ++m)
#pragma unroll
            for (int n = 0; n < 4; ++n)
#pragma unroll
                for (int r = 0; r < 4; ++r) {
                    int R  = rb + wr + m * 16 + lhi * 4 + r;
                    int Cg = cb + wc + n * 16 + l15;
                    int b = R >> 11, nseq = R & 2047;
                    int s = Cg >> 9, rm = Cg & 511, h = rm >> 6, d = rm & 63;
                    int bh = (b << 3) + h;
                    float v = acc[m][n][r];
                    if (s == 0) Qh[(bh * 2048 + nseq) * 64 + d] = f2bf(v * 0.1803368801111244f);
                    else        Kh[(bh * 2048 + nseq) * 64 + d] = f2bf(v);
                }
    }
}

// ---------------- fused two-branch attention (verified v8 structure + setprio + hoisted offsets) ----------------
#define ATTN_STEP(BUF)                                                           \
    {                                                                            \
        f32x4 s[2][2];                                                           \
        __builtin_amdgcn_s_setprio(1);                                           \
        _Pragma("unroll")                                                        \
        for (int kt = 0; kt < 2; ++kt) {                                         \
            bf16x8 kf0 = ld16(&kls[BUF][0] + koff_[kt][0]);                      \
            bf16x8 kf1 = ld16(&kls[BUF][0] + koff_[kt][1]);                      \
            _Pragma("unroll")                                                    \
            for (int qg = 0; qg < 2; ++qg) {                                     \
                s[qg][kt] = mfma16(kf0, qa[qg][0], z);                           \
                s[qg][kt] = mfma16(kf1, qa[qg][1], s[qg][kt]);                   \
            }                                                                    \
        }                                                                        \
        __builtin_amdgcn_s_setprio(0);                                           \
        bf16x8 pfd[2], pfs[2];                                                   \
        _Pragma("unroll")                                                        \
        for (int qg = 0; qg < 2; ++qg) {                                         \
            float ed[2][4], ps[2][4];                                            \
            _Pragma("unroll")                                                    \
            for (int kt = 0; kt < 2; ++kt)                                       \
                _Pragma("unroll")                                                \
                for (int r = 0; r < 4; ++r) {                                    \
                    float v = s[qg][kt][r];                                      \
                    float e = exp2_fast(v);                                      \
                    float t = fmaxf(v, 0.f);                                     \
                    float p = t * t;                                             \
                    dend[qg] += e; dens[qg] += p;                                \
                    ed[kt][r] = e; ps[kt][r] = p;                                \
                }                                                                \
            pfd[qg] = __builtin_bit_cast(bf16x8, (u32x4){                        \
                cvtpk(ed[0][0], ed[0][1]), cvtpk(ed[1][0], ed[1][1]),            \
                cvtpk(ed[0][2], ed[0][3]), cvtpk(ed[1][2], ed[1][3])});          \
            pfs[qg] = __builtin_bit_cast(bf16x8, (u32x4){                        \
                cvtpk(ps[0][0], ps[0][1]), cvtpk(ps[1][0], ps[1][1]),            \
                cvtpk(ps[0][2], ps[0][3]), cvtpk(ps[1][2], ps[1][3])});          \
        }                                                                        \
        __builtin_amdgcn_s_setprio(1);                                           \
        _Pragma("unroll")                                                        \
        for (int n = 0; n < 4; ++n) {                                            \
            bf16x8 vf = ld16(&vls[BUF][0] + voff_[n]);                           \
            _Pragma("unroll")                                                    \
            for (int qg = 0; qg < 2; ++qg) {                                     \
                accd[qg][n] = mfma16(pfd[qg], vf, accd[qg][n]);                  \
                accs[qg][n] = mfma16(pfs[qg], vf, accs[qg][n]);                  \
            }                                                                    \
        }                                                                        \
        __builtin_amdgcn_s_setprio(0);                                           \
    }

__global__ __launch_bounds__(256) void k_attn(const u16* __restrict__ Qh, const u16* __restrict__ Kh,
                                              const u16* __restrict__ VTh, const float* __restrict__ alpha,
                                              const float* __restrict__ beta, u16* __restrict__ AO) {
    __shared__ __align__(16) u16 kls[2][32 * 64];        // [buf][key][d], chunk c8 ^= key&7
    __shared__ __align__(16) u16 vls[2][64 * 32];        // [buf][d][key], chunk c4 ^= d&3
    int tid = threadIdx.x, lane = tid & 63, wid = tid >> 6;
    int l15 = lane & 15, lhi = lane >> 4;
    int wg = (blockIdx.x & 7) * 64 + (blockIdx.x >> 3);  // XCD-aware swizzle (512 % 8 == 0)
    int bh = wg >> 4;
    int qb = (wg & 15) << 7;                             // 128 queries per block
    const u16* Qp = Qh + bh * (2048 * 64);
    const u16* Kp = Kh + bh * (2048 * 64);
    const u16* Vp = VTh + bh * (2048 * 64);
    int qbase = qb + wid * 32;
    bf16x8 qa[2][2];
#pragma unroll
    for (int qg = 0; qg < 2; ++qg) {
        int row = qbase + qg * 16 + l15;
        qa[qg][0] = ld16(Qp + row * 64 + lhi * 8);
        qa[qg][1] = ld16(Qp + row * 64 + 32 + lhi * 8);
    }
    // kappa(16t+4h+r) = 8h + 4*(r>>1) + 2t + (r&1)  => P pack yields keys 8*lhi..+7
    int kap = 8 * (l15 >> 2) + 4 * ((l15 >> 1) & 1) + (l15 & 1);
    int koff_[2][2], voff_[4];
#pragma unroll
    for (int kt = 0; kt < 2; ++kt) {
        int row = kap + 2 * kt;
        koff_[kt][0] = row * 64 + ((lhi ^ (row & 7)) << 3);
        koff_[kt][1] = row * 64 + (((4 + lhi) ^ (row & 7)) << 3);
    }
#pragma unroll
    for (int n = 0; n < 4; ++n) {
        int row = n * 16 + l15;
        voff_[n] = row * 32 + ((lhi ^ (row & 3)) << 3);
    }
    f32x4 accd[2][4] = {}, accs[2][4] = {};
    float dend[2] = {}, dens[2] = {};
    const f32x4 z = {0.f, 0.f, 0.f, 0.f};

    int krow = tid >> 3, kc8 = tid & 7;
    int vrow = tid >> 2, vc4 = tid & 3;
    const u16* kg = Kp + krow * 64 + ((kc8 ^ (krow & 7)) << 3);   // pre-swizzled source
    const u16* vg = Vp + vrow * 2048 + ((vc4 ^ (vrow & 3)) << 3);

    gld16(kg, &kls[0][0] + tid * 8);
    gld16(vg, &vls[0][0] + tid * 8);
    asm volatile("s_waitcnt vmcnt(0)" ::: "memory");
    __builtin_amdgcn_s_barrier();
    const u16* kgp = kg + 32 * 64;
    const u16* vgp = vg + 32;

    for (int kb = 0; kb < 2048; kb += 64) {
        gld16(kgp, &kls[1][0] + tid * 8);
        gld16(vgp, &vls[1][0] + tid * 8);
        kgp += 32 * 64; vgp += 32;
        asm volatile("s_waitcnt vmcnt(2)" ::: "memory");
        __builtin_amdgcn_s_barrier();
        ATTN_STEP(0)
        asm volatile("" ::: "memory");
        __builtin_amdgcn_s_barrier();
        if (kb + 64 < 2048) {
            gld16(kgp, &kls[0][0] + tid * 8);
            gld16(vgp, &vls[0][0] + tid * 8);
            kgp += 32 * 64; vgp += 32;
            asm volatile("s_waitcnt vmcnt(2)" ::: "memory");
        } else {
            asm volatile("s_waitcnt vmcnt(0)" ::: "memory");
        }
        __builtin_amdgcn_s_barrier();
        ATTN_STEP(1)
        asm volatile("" ::: "memory");
        __builtin_amdgcn_s_barrier();
    }
#pragma unroll
    for (int qg = 0; qg < 2; ++qg) {
        dend[qg] += __shfl_xor(dend[qg], 16); dend[qg] += __shfl_xor(dend[qg], 32);
        dens[qg] += __shfl_xor(dens[qg], 16); dens[qg] += __shfl_xor(dens[qg], 32);
    }
    float sa = 1.f / (1.f + __expf(-alpha[0]));
    float sb = 1.f / (1.f + __expf(-beta[0]));
    float wsum = sa + sb + 1e-8f;
    float wa = sa / wsum, wb = sb / wsum;
    int b = bh >> 3, h = bh & 7;
#pragma unroll
    for (int qg = 0; qg < 2; ++qg) {
        float id[4], isr[4];
#pragma unroll
        for (int r = 0; r < 4; ++r) {
            float dd = __shfl(dend[qg], lhi * 4 + r);
            float ds = __shfl(dens[qg], lhi * 4 + r);
            id[r] = wb / dd;
            isr[r] = wa / (ds + 1e-8f);
        }
#pragma unroll
        for (int n = 0; n < 4; ++n)
#pragma unroll
            for (int r = 0; r < 4; ++r) {
                int R  = b * 2048 + qbase + qg * 16 + lhi * 4 + r;
                int Cg = h * 64 + n * 16 + l15;
                float o = isr[r] * accs[qg][n][r] + id[r] * accd[qg][n][r];
                AO[R * 512 + Cg] = f2bf(o);
            }
    }
}

// ---------------- GEMM2: out = AO @ wprojT^T + b_proj (f32 out) ----------------
// 64x64 tile, grid 1024 = 4 blocks/CU (occupancy was the binding constraint — R20).
__global__ __launch_bounds__(256) void k_gemm_proj(const u16* __restrict__ AO, const u16* __restrict__ wT,
                                                   const float* __restrict__ bproj, float* __restrict__ out) {
    __shared__ __align__(16) u16 at[64 * 64];
    __shared__ __align__(16) u16 bt[64 * 64];
    int tid = threadIdx.x, lane = tid & 63, wid = tid >> 6;
    int tm = blockIdx.x >> 3, tn = blockIdx.x & 7;
    int rb = tm * 64, cb = tn * 64;
    int wr = (wid >> 1) * 32, wc = (wid & 1) * 32;
    int l15 = lane & 15, lhi = lane >> 4;
    f32x4 acc[2][2] = {};
    for (int kk = 0; kk < 512; kk += 64) {
        stage64x64(AO + rb * 512 + kk, 512, at, tid);
        stage64x64(wT + cb * 512 + kk, 512, bt, tid);
        __syncthreads();
        bf16x8 af[2][2], bfr[2][2];
#pragma unroll
        for (int m = 0; m < 2; ++m) {
            int row = wr + m * 16 + l15;
            af[m][0] = frag(at, row, lhi);
            af[m][1] = frag(at, row, 4 + lhi);
        }
#pragma unroll
        for (int n = 0; n < 2; ++n) {
            int row = wc + n * 16 + l15;
            bfr[n][0] = frag(bt, row, lhi);
            bfr[n][1] = frag(bt, row, 4 + lhi);
        }
#pragma unroll
        for (int m = 0; m < 2; ++m)
#pragma unroll
            for (int n = 0; n < 2; ++n) {
                acc[m][n] = mfma16(af[m][0], bfr[n][0], acc[m][n]);
                acc[m][n] = mfma16(af[m][1], bfr[n][1], acc[m][n]);
            }
        __syncthreads();
    }
#pragma unroll
    for (int m = 0; m < 2; ++m)
#pragma unroll
        for (int n = 0; n < 2; ++n)
#pragma unroll
            for (int r = 0; r < 4; ++r) {
                int R  = rb + wr + m * 16 + lhi * 4 + r;
                int Cg = cb + wc + n * 16 + l15;
                out[R * 512 + Cg] = acc[m][n][r] + bproj[Cg];
            }
}

extern "C" void kernel_launch(void* const* d_in, const int* in_sizes, int n_in,
                              void* d_out, int out_size, void* d_ws, size_t ws_size,
                              hipStream_t stream) {
    const float* x      = (const float*)d_in[0];
    const float* w_qkv  = (const float*)d_in[1];
    const float* alpha  = (const float*)d_in[2];
    const float* beta   = (const float*)d_in[3];
    const float* w_proj = (const float*)d_in[4];
    const float* b_proj = (const float*)d_in[5];
    float* out = (float*)d_out;
    char* w = (char*)d_ws;
    u16* xb     = (u16*)(w);                 //  8,388,608 B
    u16* wqkvT  = (u16*)(w + 8388608);       //  1,572,864 B
    u16* wprojT = (u16*)(w + 9961472);       //    524,288 B
    u16* Qh     = (u16*)(w + 10485760);      //  8,388,608 B
    u16* Kh     = (u16*)(w + 18874368);      //  8,388,608 B
    u16* VTh    = (u16*)(w + 27262976);      //  8,388,608 B
    u16* AO     = xb;                        // alias: xb dead after k_gemm_qkv

    k_prep<<<dim3(3072), dim3(256), 0, stream>>>(x, xb, w_qkv, wqkvT, w_proj, wprojT);
    k_gemm_qkv<<<dim3(768), dim3(256), 0, stream>>>(xb, wqkvT, Qh, Kh, VTh);
    k_attn<<<dim3(512), dim3(256), 0, stream>>>(Qh, Kh, VTh, alpha, beta, AO);
    k_gemm_proj<<<dim3(1024), dim3(256), 0, stream>>>(AO, wprojT, b_proj, out);
}

// Round 22
// 123.521 us; speedup vs baseline: 1.0189x; 1.0189x over previous
//
#include <hip/hip_runtime.h>

typedef unsigned short u16;
typedef unsigned int   u32;
typedef __attribute__((ext_vector_type(8))) __bf16 bf16x8;
typedef __attribute__((ext_vector_type(4))) float  f32x4;
typedef __attribute__((ext_vector_type(4))) u32    u32x4;

#define AS1q __attribute__((address_space(1)))
#define AS3q __attribute__((address_space(3)))

static __device__ __forceinline__ u16 f2bf(float f) {
    u32 u = __builtin_bit_cast(u32, f);
    u32 r = u + 0x7FFFu + ((u >> 16) & 1u);   // round-to-nearest-even
    return (u16)(r >> 16);
}

static __device__ __forceinline__ bf16x8 ld16(const u16* p) {
    return __builtin_bit_cast(bf16x8, *(const float4*)(const void*)p);
}

static __device__ __forceinline__ f32x4 mfma16(bf16x8 a, bf16x8 b, f32x4 c) {
    return __builtin_amdgcn_mfma_f32_16x16x32_bf16(a, b, c, 0, 0, 0);
}

static __device__ __forceinline__ void gld16(const u16* g, u16* l) {
    __builtin_amdgcn_global_load_lds((const AS1q u32*)g, (AS3q u32*)l, 16, 0, 0);
}

static __device__ __forceinline__ float exp2_fast(float v) {
    float e;
    asm("v_exp_f32 %0, %1" : "=v"(e) : "v"(v));
    return e;
}

static __device__ __forceinline__ u32 cvtpk(float lo, float hi_) {
    u32 d;
    asm("v_cvt_pk_bf16_f32 %0, %1, %2" : "=v"(d) : "v"(lo), "v"(hi_));
    return d;
}

// ---------------- fused prep: cast x -> bf16, transpose+cast w_qkv & w_proj ----------------
// blocks [0,4096): cast x (1M float4s). [4096,4864): w_qkv^T (48x16 tiles). [4864,5120): w_proj^T (16x16).
__global__ __launch_bounds__(256) void k_prep(const float* __restrict__ x, u16* __restrict__ xb,
                                              const float* __restrict__ wqkv, u16* __restrict__ wqkvT,
                                              const float* __restrict__ wproj, u16* __restrict__ wprojT) {
    __shared__ float tile[32][33];
    int bid = blockIdx.x, tid = threadIdx.x;
    if (bid < 4096) {
        int i = bid * 256 + tid;
        float4 v = ((const float4*)x)[i];
        ushort4 o;
        o.x = f2bf(v.x); o.y = f2bf(v.y); o.z = f2bf(v.z); o.w = f2bf(v.w);
        ((ushort4*)xb)[i] = o;
        return;
    }
    const float* in; u16* out; int K, Nn, bx, by;
    if (bid < 4864) {
        int b2 = bid - 4096;            // w_qkv: 1536 x 512 -> [1536][512]
        in = wqkv; out = wqkvT; K = 512; Nn = 1536;
        bx = b2 % 48; by = b2 / 48;
    } else {
        int b3 = bid - 4864;            // w_proj: 512 x 512
        in = wproj; out = wprojT; K = 512; Nn = 512;
        bx = b3 % 16; by = b3 / 16;
    }
    int tx = tid & 31, ty = tid >> 5;
    int k0 = by * 32, n0 = bx * 32;
#pragma unroll
    for (int i = 0; i < 4; ++i)
        tile[ty + i * 8][tx] = in[(k0 + ty + i * 8) * Nn + n0 + tx];
    __syncthreads();
#pragma unroll
    for (int i = 0; i < 4; ++i)
        out[(n0 + ty + i * 8) * K + k0 + tx] = f2bf(tile[tx][ty + i * 8]);
}

// ---------- shared GEMM pieces: XOR-swizzled LDS staging ----------
static __device__ __forceinline__ void stage128x64(const u16* __restrict__ gbase, int ld,
                                                   u16* lds, int tid) {
    int wid = tid >> 6;
#pragma unroll
    for (int i = 0; i < 4; ++i) {
        int idx = i * 256 + tid;
        int row = idx >> 3, c8 = idx & 7;
        int csw = c8 ^ (row & 7);
        gld16(gbase + row * ld + csw * 8, lds + (i * 256 + wid * 64) * 8);
    }
}

static __device__ __forceinline__ void stage64x64(const u16* __restrict__ gbase, int ld,
                                                  u16* lds, int tid) {
    int wid = tid >> 6;
#pragma unroll
    for (int i = 0; i < 2; ++i) {
        int idx = i * 256 + tid;
        int row = idx >> 3, c8 = idx & 7;
        int csw = c8 ^ (row & 7);
        gld16(gbase + row * ld + csw * 8, lds + (i * 256 + wid * 64) * 8);
    }
}

static __device__ __forceinline__ bf16x8 frag(const u16* lds, int row, int col16) {
    return ld16(lds + row * 64 + ((col16 ^ (row & 7)) << 3));
}

// ---------------- GEMM1: qkv = xb @ wqkvT^T, scatter to Q/K/VT bf16 ----------------
// Q pre-scaled by 0.125*log2(e). V blocks (tn>=8) store VT via ushort4 (4 consecutive nseq).
__global__ __launch_bounds__(256) void k_gemm_qkv(const u16* __restrict__ xb, const u16* __restrict__ wT,
                                                  u16* __restrict__ Qh, u16* __restrict__ Kh,
                                                  u16* __restrict__ VTh) {
    __shared__ __align__(16) u16 at[128 * 64];
    __shared__ __align__(16) u16 bt[128 * 64];
    int tid = threadIdx.x, lane = tid & 63, wid = tid >> 6;
    int tm = blockIdx.x / 12, tn = blockIdx.x % 12;
    int rb = tm * 128, cb = tn * 128;
    int wr = (wid >> 1) * 64, wc = (wid & 1) * 64;
    int l15 = lane & 15, lhi = lane >> 4;
    f32x4 acc[4][4] = {};
    for (int kk = 0; kk < 512; kk += 64) {
        stage128x64(xb + rb * 512 + kk, 512, at, tid);
        stage128x64(wT + cb * 512 + kk, 512, bt, tid);
        __syncthreads();
        bf16x8 af[4][2], bfr[4][2];
#pragma unroll
        for (int m = 0; m < 4; ++m) {
            int row = wr + m * 16 + l15;
            af[m][0] = frag(at, row, lhi);
            af[m][1] = frag(at, row, 4 + lhi);
        }
#pragma unroll
        for (int n = 0; n < 4; ++n) {
            int row = wc + n * 16 + l15;
            bfr[n][0] = frag(bt, row, lhi);
            bfr[n][1] = frag(bt, row, 4 + lhi);
        }
#pragma unroll
        for (int m = 0; m < 4; ++m)
#pragma unroll
            for (int n = 0; n < 4; ++n) {
                acc[m][n] = mfma16(af[m][0], bfr[n][0], acc[m][n]);
                acc[m][n] = mfma16(af[m][1], bfr[n][1], acc[m][n]);
            }
        __syncthreads();
    }
    if (tn >= 8) {
        // pure-V block: for fixed (m,n) the 4 r-values are 4 consecutive nseq in VT -> one 8B store
#pragma unroll
        for (int m = 0; m < 4; ++m)
#pragma unroll
            for (int n = 0; n < 4; ++n) {
                ushort4 o4;
                o4.x = f2bf(acc[m][n][0]); o4.y = f2bf(acc[m][n][1]);
                o4.z = f2bf(acc[m][n][2]); o4.w = f2bf(acc[m][n][3]);
                int R0 = rb + wr + m * 16 + lhi * 4;          // nseq base (mult of 4)
                int Cg = cb + wc + n * 16 + l15;
                int b = R0 >> 11, nseq = R0 & 2047;
                int rm = Cg & 511, h = rm >> 6, d = rm & 63;
                int bh = (b << 3) + h;
                *(ushort4*)&VTh[(bh * 64 + d) * 2048 + nseq] = o4;
            }
    } else {
#pragma unroll
        for (int m = 0; m < 4; ++m)
#pragma unroll
            for (int n = 0; n < 4; ++n)
#pragma unroll
                for (int r = 0; r < 4; ++r) {
                    int R  = rb + wr + m * 16 + lhi * 4 + r;
                    int Cg = cb + wc + n * 16 + l15;
                    int b = R >> 11, nseq = R & 2047;
                    int s = Cg >> 9, rm = Cg & 511, h = rm >> 6, d = rm & 63;
                    int bh = (b << 3) + h;
                    float v = acc[m][n][r];
                    if (s == 0) Qh[(bh * 2048 + nseq) * 64 + d] = f2bf(v * 0.1803368801111244f);
                    else        Kh[(bh * 2048 + nseq) * 64 + d] = f2bf(v);
                }
    }
}

// ---------------- fused two-branch attention (verified v8 structure + setprio + hoisted offsets) ----------------
#define ATTN_STEP(BUF)                                                           \
    {                                                                            \
        f32x4 s[2][2];                                                           \
        __builtin_amdgcn_s_setprio(1);                                           \
        _Pragma("unroll")                                                        \
        for (int kt = 0; kt < 2; ++kt) {                                         \
            bf16x8 kf0 = ld16(&kls[BUF][0] + koff_[kt][0]);                      \
            bf16x8 kf1 = ld16(&kls[BUF][0] + koff_[kt][1]);                      \
            _Pragma("unroll")                                                    \
            for (int qg = 0; qg < 2; ++qg) {                                     \
                s[qg][kt] = mfma16(kf0, qa[qg][0], z);                           \
                s[qg][kt] = mfma16(kf1, qa[qg][1], s[qg][kt]);                   \
            }                                                                    \
        }                                                                        \
        __builtin_amdgcn_s_setprio(0);                                           \
        bf16x8 pfd[2], pfs[2];                                                   \
        _Pragma("unroll")                                                        \
        for (int qg = 0; qg < 2; ++qg) {                                         \
            float ed[2][4], ps[2][4];                                            \
            _Pragma("unroll")                                                    \
            for (int kt = 0; kt < 2; ++kt)                                       \
                _Pragma("unroll")                                                \
                for (int r = 0; r < 4; ++r) {                                    \
                    float v = s[qg][kt][r];                                      \
                    float e = exp2_fast(v);                                      \
                    float t = fmaxf(v, 0.f);                                     \
                    float p = t * t;                                             \
                    dend[qg] += e; dens[qg] += p;                                \
                    ed[kt][r] = e; ps[kt][r] = p;                                \
                }                                                                \
            pfd[qg] = __builtin_bit_cast(bf16x8, (u32x4){                        \
                cvtpk(ed[0][0], ed[0][1]), cvtpk(ed[1][0], ed[1][1]),            \
                cvtpk(ed[0][2], ed[0][3]), cvtpk(ed[1][2], ed[1][3])});          \
            pfs[qg] = __builtin_bit_cast(bf16x8, (u32x4){                        \
                cvtpk(ps[0][0], ps[0][1]), cvtpk(ps[1][0], ps[1][1]),            \
                cvtpk(ps[0][2], ps[0][3]), cvtpk(ps[1][2], ps[1][3])});          \
        }                                                                        \
        __builtin_amdgcn_s_setprio(1);                                           \
        _Pragma("unroll")                                                        \
        for (int n = 0; n < 4; ++n) {                                            \
            bf16x8 vf = ld16(&vls[BUF][0] + voff_[n]);                           \
            _Pragma("unroll")                                                    \
            for (int qg = 0; qg < 2; ++qg) {                                     \
                accd[qg][n] = mfma16(pfd[qg], vf, accd[qg][n]);                  \
                accs[qg][n] = mfma16(pfs[qg], vf, accs[qg][n]);                  \
            }                                                                    \
        }                                                                        \
        __builtin_amdgcn_s_setprio(0);                                           \
    }

__global__ __launch_bounds__(256) void k_attn(const u16* __restrict__ Qh, const u16* __restrict__ Kh,
                                              const u16* __restrict__ VTh, const float* __restrict__ alpha,
                                              const float* __restrict__ beta, u16* __restrict__ AO) {
    __shared__ __align__(16) u16 kls[2][32 * 64];        // [buf][key][d], chunk c8 ^= key&7
    __shared__ __align__(16) u16 vls[2][64 * 32];        // [buf][d][key], chunk c4 ^= d&3
    int tid = threadIdx.x, lane = tid & 63, wid = tid >> 6;
    int l15 = lane & 15, lhi = lane >> 4;
    int wg = (blockIdx.x & 7) * 64 + (blockIdx.x >> 3);  // XCD-aware swizzle (512 % 8 == 0)
    int bh = wg >> 4;
    int qb = (wg & 15) << 7;                             // 128 queries per block
    const u16* Qp = Qh + bh * (2048 * 64);
    const u16* Kp = Kh + bh * (2048 * 64);
    const u16* Vp = VTh + bh * (2048 * 64);
    int qbase = qb + wid * 32;
    bf16x8 qa[2][2];
#pragma unroll
    for (int qg = 0; qg < 2; ++qg) {
        int row = qbase + qg * 16 + l15;
        qa[qg][0] = ld16(Qp + row * 64 + lhi * 8);
        qa[qg][1] = ld16(Qp + row * 64 + 32 + lhi * 8);
    }
    // kappa(16t+4h+r) = 8h + 4*(r>>1) + 2t + (r&1)  => P pack yields keys 8*lhi..+7
    int kap = 8 * (l15 >> 2) + 4 * ((l15 >> 1) & 1) + (l15 & 1);
    int koff_[2][2], voff_[4];
#pragma unroll
    for (int kt = 0; kt < 2; ++kt) {
        int row = kap + 2 * kt;
        koff_[kt][0] = row * 64 + ((lhi ^ (row & 7)) << 3);
        koff_[kt][1] = row * 64 + (((4 + lhi) ^ (row & 7)) << 3);
    }
#pragma unroll
    for (int n = 0; n < 4; ++n) {
        int row = n * 16 + l15;
        voff_[n] = row * 32 + ((lhi ^ (row & 3)) << 3);
    }
    f32x4 accd[2][4] = {}, accs[2][4] = {};
    float dend[2] = {}, dens[2] = {};
    const f32x4 z = {0.f, 0.f, 0.f, 0.f};

    int krow = tid >> 3, kc8 = tid & 7;
    int vrow = tid >> 2, vc4 = tid & 3;
    const u16* kg = Kp + krow * 64 + ((kc8 ^ (krow & 7)) << 3);   // pre-swizzled source
    const u16* vg = Vp + vrow * 2048 + ((vc4 ^ (vrow & 3)) << 3);

    gld16(kg, &kls[0][0] + tid * 8);
    gld16(vg, &vls[0][0] + tid * 8);
    asm volatile("s_waitcnt vmcnt(0)" ::: "memory");
    __builtin_amdgcn_s_barrier();
    const u16* kgp = kg + 32 * 64;
    const u16* vgp = vg + 32;

    for (int kb = 0; kb < 2048; kb += 64) {
        gld16(kgp, &kls[1][0] + tid * 8);
        gld16(vgp, &vls[1][0] + tid * 8);
        kgp += 32 * 64; vgp += 32;
        asm volatile("s_waitcnt vmcnt(2)" ::: "memory");
        __builtin_amdgcn_s_barrier();
        ATTN_STEP(0)
        asm volatile("" ::: "memory");
        __builtin_amdgcn_s_barrier();
        if (kb + 64 < 2048) {
            gld16(kgp, &kls[0][0] + tid * 8);
            gld16(vgp, &vls[0][0] + tid * 8);
            kgp += 32 * 64; vgp += 32;
            asm volatile("s_waitcnt vmcnt(2)" ::: "memory");
        } else {
            asm volatile("s_waitcnt vmcnt(0)" ::: "memory");
        }
        __builtin_amdgcn_s_barrier();
        ATTN_STEP(1)
        asm volatile("" ::: "memory");
        __builtin_amdgcn_s_barrier();
    }
#pragma unroll
    for (int qg = 0; qg < 2; ++qg) {
        dend[qg] += __shfl_xor(dend[qg], 16); dend[qg] += __shfl_xor(dend[qg], 32);
        dens[qg] += __shfl_xor(dens[qg], 16); dens[qg] += __shfl_xor(dens[qg], 32);
    }
    float sa = 1.f / (1.f + __expf(-alpha[0]));
    float sb = 1.f / (1.f + __expf(-beta[0]));
    float wsum = sa + sb + 1e-8f;
    float wa = sa / wsum, wb = sb / wsum;
    int b = bh >> 3, h = bh & 7;
#pragma unroll
    for (int qg = 0; qg < 2; ++qg) {
        float id[4], isr[4];
#pragma unroll
        for (int r = 0; r < 4; ++r) {
            float dd = __shfl(dend[qg], lhi * 4 + r);
            float ds = __shfl(dens[qg], lhi * 4 + r);
            id[r] = wb / dd;
            isr[r] = wa / (ds + 1e-8f);
        }
#pragma unroll
        for (int n = 0; n < 4; ++n)
#pragma unroll
            for (int r = 0; r < 4; ++r) {
                int R  = b * 2048 + qbase + qg * 16 + lhi * 4 + r;
                int Cg = h * 64 + n * 16 + l15;
                float o = isr[r] * accs[qg][n][r] + id[r] * accd[qg][n][r];
                AO[R * 512 + Cg] = f2bf(o);
            }
    }
}

// ---------------- GEMM2: out = AO @ wprojT^T + b_proj (f32 out) ----------------
// 64x128 tile, grid 512 = 2 blocks/CU (R20 optimum; 64x64/1024 and 128x128/256 both worse).
__global__ __launch_bounds__(256) void k_gemm_proj(const u16* __restrict__ AO, const u16* __restrict__ wT,
                                                   const float* __restrict__ bproj, float* __restrict__ out) {
    __shared__ __align__(16) u16 at[64 * 64];
    __shared__ __align__(16) u16 bt[128 * 64];
    int tid = threadIdx.x, lane = tid & 63, wid = tid >> 6;
    int tm = blockIdx.x >> 2, tn = blockIdx.x & 3;
    int rb = tm * 64, cb = tn * 128;
    int wr = (wid >> 1) * 32, wc = (wid & 1) * 64;
    int l15 = lane & 15, lhi = lane >> 4;
    f32x4 acc[2][4] = {};
    for (int kk = 0; kk < 512; kk += 64) {
        stage64x64(AO + rb * 512 + kk, 512, at, tid);
        stage128x64(wT + cb * 512 + kk, 512, bt, tid);
        __syncthreads();
        bf16x8 af[2][2], bfr[4][2];
#pragma unroll
        for (int m = 0; m < 2; ++m) {
            int row = wr + m * 16 + l15;
            af[m][0] = frag(at, row, lhi);
            af[m][1] = frag(at, row, 4 + lhi);
        }
#pragma unroll
        for (int n = 0; n < 4; ++n) {
            int row = wc + n * 16 + l15;
            bfr[n][0] = frag(bt, row, lhi);
            bfr[n][1] = frag(bt, row, 4 + lhi);
        }
#pragma unroll
        for (int m = 0; m < 2; ++m)
#pragma unroll
            for (int n = 0; n < 4; ++n) {
                acc[m][n] = mfma16(af[m][0], bfr[n][0], acc[m][n]);
                acc[m][n] = mfma16(af[m][1], bfr[n][1], acc[m][n]);
            }
        __syncthreads();
    }
#pragma unroll
    for (int m = 0; m < 2; ++m)
#pragma unroll
        for (int n = 0; n < 4; ++n)
#pragma unroll
            for (int r = 0; r < 4; ++r) {
                int R  = rb + wr + m * 16 + lhi * 4 + r;
                int Cg = cb + wc + n * 16 + l15;
                out[R * 512 + Cg] = acc[m][n][r] + bproj[Cg];
            }
}

extern "C" void kernel_launch(void* const* d_in, const int* in_sizes, int n_in,
                              void* d_out, int out_size, void* d_ws, size_t ws_size,
                              hipStream_t stream) {
    const float* x      = (const float*)d_in[0];
    const float* w_qkv  = (const float*)d_in[1];
    const float* alpha  = (const float*)d_in[2];
    const float* beta   = (const float*)d_in[3];
    const float* w_proj = (const float*)d_in[4];
    const float* b_proj = (const float*)d_in[5];
    float* out = (float*)d_out;
    char* w = (char*)d_ws;
    u16* xb     = (u16*)(w);                 //  8,388,608 B
    u16* wqkvT  = (u16*)(w + 8388608);       //  1,572,864 B
    u16* wprojT = (u16*)(w + 9961472);       //    524,288 B
    u16* Qh     = (u16*)(w + 10485760);      //  8,388,608 B
    u16* Kh     = (u16*)(w + 18874368);      //  8,388,608 B
    u16* VTh    = (u16*)(w + 27262976);      //  8,388,608 B
    u16* AO     = xb;                        // alias: xb dead after k_gemm_qkv

    k_prep<<<dim3(5120), dim3(256), 0, stream>>>(x, xb, w_qkv, wqkvT, w_proj, wprojT);
    k_gemm_qkv<<<dim3(768), dim3(256), 0, stream>>>(xb, wqkvT, Qh, Kh, VTh);
    k_attn<<<dim3(512), dim3(256), 0, stream>>>(Qh, Kh, VTh, alpha, beta, AO);
    k_gemm_proj<<<dim3(512), dim3(256), 0, stream>>>(AO, wprojT, b_proj, out);
}